// Round 2
// baseline (532.535 us; speedup 1.0000x reference)
//
#include <hip/hip_runtime.h>

#define N_DIM 512
#define M_DIM 512
#define BIGF  1.0e8f

// Soft-DTW forward DP, anti-diagonal wavefront.
// One block per batch, thread j owns column j. Step t computes cell (t-j, j).
// Neighbor (j-1) values move via __shfl_up within a wave; across wave
// boundaries via parity-double-buffered LDS + one barrier per step.
__global__ __launch_bounds__(M_DIM, 1) void softdtw_kernel(const float* __restrict__ D,
                                                           float* __restrict__ R) {
    const int b    = blockIdx.x;
    const int j    = threadIdx.x;       // column owned by this thread
    const int lane = j & 63;
    const int w    = j >> 6;            // wave id 0..7
    constexpr int NW = M_DIM / 64;      // 8 waves

    const float* __restrict__ Db = D + (size_t)b * N_DIM * M_DIM;
    float* __restrict__ Rb       = R + (size_t)b * N_DIM * M_DIM;

    __shared__ float sb[2][NW];         // per-wave lane-63 boundary, parity buffered

    float r1       = BIGF;  // own R at previous step (R[i-1][j] once active)
    float leftPrev = BIGF;  // neighbor's value from step t-2 (the diagonal)

    // D prefetch ring (depth 2), clamped addresses for inactive steps
    float dA, dB;
    {
        int c0 = min(max(0 - j, 0), N_DIM - 1);
        dA = Db[(size_t)c0 * M_DIM + j];
        int c1 = min(max(1 - j, 0), N_DIM - 1);
        dB = Db[(size_t)c1 * M_DIM + j];
    }

    const int wm1 = (w > 0) ? (w - 1) : 0;

    for (int t = 0; t < N_DIM + M_DIM; t += 2) {
        // ---------------- step t (consumes dA) ----------------
        {
            const int i = t - j;
            float leftRaw = __shfl_up(r1, 1);
            float ldsv = sb[(t + 1) & 1][wm1];          // broadcast read (uniform per wave)
            if (lane == 0) leftRaw = (w > 0) ? ldsv : BIGF;

            // prefetch D for step t+2
            int ipc = min(max(t + 2 - j, 0), N_DIM - 1);
            float dNew = Db[(size_t)ipc * M_DIM + j];

            const bool active = (i >= 0) && (i < N_DIM);
            float up   = (i == 0) ? BIGF : r1;
            float diag = (j == 0) ? ((t == 0) ? 0.0f : BIGF)
                                  : ((i == 0) ? BIGF : leftPrev);
            float left = (j == 0) ? BIGF : leftRaw;

            float m = fminf(fminf(diag, up), left);
            float s = __expf(m - diag) + __expf(m - up) + __expf(m - left);
            float r = dA + m - __logf(s);

            if (active) {
                Rb[(size_t)i * M_DIM + j] = r;
                r1 = r;
            }
            leftPrev = leftRaw;
            dA = dNew;

            if (lane == 63) sb[t & 1][w] = r1;
            __syncthreads();
        }
        // ---------------- step t+1 (consumes dB) ----------------
        {
            const int t1 = t + 1;
            const int i  = t1 - j;
            float leftRaw = __shfl_up(r1, 1);
            float ldsv = sb[(t1 + 1) & 1][wm1];
            if (lane == 0) leftRaw = (w > 0) ? ldsv : BIGF;

            int ipc = min(max(t1 + 2 - j, 0), N_DIM - 1);
            float dNew = Db[(size_t)ipc * M_DIM + j];

            const bool active = (i >= 0) && (i < N_DIM);
            float up   = (i == 0) ? BIGF : r1;
            float diag = (j == 0) ? BIGF                      // t1 >= 1 always
                                  : ((i == 0) ? BIGF : leftPrev);
            float left = (j == 0) ? BIGF : leftRaw;

            float m = fminf(fminf(diag, up), left);
            float s = __expf(m - diag) + __expf(m - up) + __expf(m - left);
            float r = dB + m - __logf(s);

            if (active) {
                Rb[(size_t)i * M_DIM + j] = r;
                r1 = r;
            }
            leftPrev = leftRaw;
            dB = dNew;

            if (lane == 63) sb[t1 & 1][w] = r1;
            __syncthreads();
        }
    }
}

extern "C" void kernel_launch(void* const* d_in, const int* in_sizes, int n_in,
                              void* d_out, int out_size, void* d_ws, size_t ws_size,
                              hipStream_t stream) {
    const float* x = (const float*)d_in[0];
    float* out     = (float*)d_out;
    const int B    = in_sizes[0] / (N_DIM * M_DIM);   // trailing singleton dim folds away
    softdtw_kernel<<<dim3(B), dim3(M_DIM), 0, stream>>>(x, out);
}

// Round 3
// 428.649 us; speedup vs baseline: 1.2424x; 1.2424x over previous
//
#include <hip/hip_runtime.h>

#define N_DIM 512
#define M_DIM 512
#define BIGF  1.0e8f

// Soft-DTW forward DP, banded wavefront: ONE wave per batch.
// Lane l owns columns [8l, 8l+8). At step s, lane l computes row i = s - l
// across its 8 columns (serial within the lane, registers only).
// Cross-lane boundary (left & diag of column 8l) comes from lane l-1's
// prev[7] via one __shfl_up per step (+ one register of history for diag).
// No LDS, no barriers.
__global__ __launch_bounds__(64, 1) void softdtw_kernel(const float* __restrict__ D,
                                                        float* __restrict__ R) {
    const int b  = blockIdx.x;
    const int l  = threadIdx.x;          // lane 0..63
    const int c0 = l << 3;               // first of 8 owned columns

    const float* __restrict__ Db = D + (size_t)b * N_DIM * M_DIM;
    float*       __restrict__ Rb = R + (size_t)b * N_DIM * M_DIM;

    float prev[8];                       // R[i-1][c0 .. c0+7]
    #pragma unroll
    for (int k = 0; k < 8; ++k) prev[k] = BIGF;

    float bDiag = BIGF;                  // R[i-1][c0-1] (from lane l-1, one step ago)

    // D for the current row (row 0 pre-activation; clamped prefetch keeps it valid)
    float4 dA = *(const float4*)(Db + c0);
    float4 dB = *(const float4*)(Db + c0 + 4);

    const int NSTEP = N_DIM + 63;        // 575 steps; lane l active for s in [l, l+511]
    for (int s = 0; s < NSTEP; ++s) {
        // boundary from lane l-1: its prev[7] == R[s-l][8l-1] at step start
        float bLeft = __shfl_up(prev[7], 1);
        if (l == 0) bLeft = BIGF;

        const int i = s - l;

        // prefetch next row's D (clamped when inactive; L1/L2 hit)
        const int inext = min(max(i + 1, 0), N_DIM - 1);
        const float4 nA = *(const float4*)(Db + (size_t)inext * M_DIM + c0);
        const float4 nB = *(const float4*)(Db + (size_t)inext * M_DIM + c0 + 4);

        if (0 <= i && i < N_DIM) {
            float dg0 = bDiag;
            if (l == 0) dg0 = (i == 0) ? 0.0f : BIGF;   // R[-1][-1]=0 start cell
            float left = bLeft;

            const float dcell[8] = {dA.x, dA.y, dA.z, dA.w, dB.x, dB.y, dB.z, dB.w};
            float out[8];
            #pragma unroll
            for (int c = 0; c < 8; ++c) {
                const float up   = prev[c];
                const float diag = (c == 0) ? dg0 : prev[c - 1];
                const float z    = fminf(diag, up);      // off-chain vs left
                const float m    = fminf(z, left);
                const float ssum = __expf(m - diag) + __expf(m - up) + __expf(m - left);
                const float r    = dcell[c] + m - __logf(ssum);
                out[c] = r;
                left   = r;
            }
            #pragma unroll
            for (int c = 0; c < 8; ++c) prev[c] = out[c];

            float4* ro = (float4*)(Rb + (size_t)i * M_DIM + c0);
            ro[0] = make_float4(out[0], out[1], out[2], out[3]);
            ro[1] = make_float4(out[4], out[5], out[6], out[7]);
        }

        bDiag = bLeft;
        dA = nA; dB = nB;
    }
}

extern "C" void kernel_launch(void* const* d_in, const int* in_sizes, int n_in,
                              void* d_out, int out_size, void* d_ws, size_t ws_size,
                              hipStream_t stream) {
    const float* x = (const float*)d_in[0];
    float* out     = (float*)d_out;
    const int B    = in_sizes[0] / (N_DIM * M_DIM);
    softdtw_kernel<<<dim3(B), dim3(64), 0, stream>>>(x, out);
}

// Round 4
// 272.087 us; speedup vs baseline: 1.9572x; 1.5754x over previous
//
#include <hip/hip_runtime.h>

#define N_DIM 512
#define M_DIM 512
#define NPAIR 256          // 512 rows as 256 row-pairs
#define TSTEPS 321         // 256 + 63 skew, padded to multiple of 3

// Soft-DTW forward DP, exp-domain banded wavefront. One wave per batch.
// Lane l owns columns [8l, 8l+8). Step s: lane l computes row-pair t = s-l
// (rows 2t, 2t+1). E[j] = exp(G - R[i][j]) turns the softmin recurrence into
// a single FMA per cell; logs/exps are off the serial chain.
__global__ __launch_bounds__(64, 1) void softdtw_kernel(const float* __restrict__ D,
                                                        float* __restrict__ R) {
    const int b  = blockIdx.x;
    const int l  = threadIdx.x;      // lane 0..63
    const int c0 = l << 3;

    const float* __restrict__ Db = D + (size_t)b * N_DIM * M_DIM;
    float*       __restrict__ Rb = R + (size_t)b * N_DIM * M_DIM;

    // ---- persistent state ----
    float Ep[8];                      // prev row (row 2t-1) E-values, frame F
    #pragma unroll
    for (int k = 0; k < 8; ++k) Ep[k] = 0.0f;
    float F = 0.0f;                   // frame of Ep (and exported boundary regs)
    float G = 0.0f;                   // frame chosen for the upcoming pair
    float fQ = 0.0f;                  // exp(G - F), precomputed off-chain
    float expA7 = 0.0f, expB7 = 0.0f; // exported E[7] of last pair's rows A,B
    float E7hB = 0.0f, Fh = 0.0f;     // history: lane l-1's (expB7, F) one step ago

    auto loadrow = [&](int r, float4& a, float4& c) {
        r = min(max(r, 0), N_DIM - 1);
        const float4* p = (const float4*)(Db + (size_t)r * M_DIM + c0);
        a = p[0];
        c = p[1];
    };

    // ---- D ring: 3 slots of row-pairs + current converted pair ----
    float endA[8], endB[8];           // exp(-d) for pair t (consumed this step)
    float4 s0A0, s0A1, s0B0, s0B1;    // pair t+1
    float4 s1A0, s1A1, s1B0, s1B1;    // pair t+2
    float4 s2A0, s2A1, s2B0, s2B1;    // pair t+3
    {
        const int t0 = -l;
        float4 rA0, rA1, rB0, rB1;
        loadrow(2 * t0,     rA0, rA1);
        loadrow(2 * t0 + 1, rB0, rB1);
        loadrow(2 * (t0 + 1),     s0A0, s0A1);
        loadrow(2 * (t0 + 1) + 1, s0B0, s0B1);
        loadrow(2 * (t0 + 2),     s1A0, s1A1);
        loadrow(2 * (t0 + 2) + 1, s1B0, s1B1);
        loadrow(2 * (t0 + 3),     s2A0, s2A1);
        loadrow(2 * (t0 + 3) + 1, s2B0, s2B1);
        endA[0] = __expf(-rA0.x); endA[1] = __expf(-rA0.y);
        endA[2] = __expf(-rA0.z); endA[3] = __expf(-rA0.w);
        endA[4] = __expf(-rA1.x); endA[5] = __expf(-rA1.y);
        endA[6] = __expf(-rA1.z); endA[7] = __expf(-rA1.w);
        endB[0] = __expf(-rB0.x); endB[1] = __expf(-rB0.y);
        endB[2] = __expf(-rB0.z); endB[3] = __expf(-rB0.w);
        endB[4] = __expf(-rB1.x); endB[5] = __expf(-rB1.y);
        endB[6] = __expf(-rB1.z); endB[7] = __expf(-rB1.w);
    }

    // one wavefront step; (qA0..qB1) is the ring slot to convert & reload
    auto step_body = [&](int s, float4& qA0, float4& qA1, float4& qB0, float4& qB1) {
        // boundary state from lane l-1 (as of end of step s-1)
        float E7sA = __shfl_up(expA7, 1);
        float E7sB = __shfl_up(expB7, 1);
        float Fs   = __shfl_up(F, 1);

        const int t = s - l;
        const bool active = (t >= 0) && (t < NPAIR);

        if (active) {
            const int i0 = t << 1;
            float g, factor, eLeftA, eDiagA0;
            if (t == 0) {
                if (l == 0) { g = 0.0f; factor = 0.0f; eLeftA = 0.0f; eDiagA0 = 1.0f; }
                else {
                    g       = Fs - __logf(E7sA);   // adopt incoming boundary value
                    factor  = 1.0f / E7sA;         // = exp(g - Fs)
                    eLeftA  = 1.0f;                 // exp(g - r_left) with g = r_left
                    eDiagA0 = 0.0f;                 // diag of row 0 is BIG
                }
                fQ = 0.0f;                          // prev row all BIG
            } else {
                g       = G;
                factor  = __expf(g - Fs);
                eLeftA  = (l == 0) ? 0.0f : E7sA * factor;
                eDiagA0 = (l == 0) ? 0.0f : E7hB * __expf(g - Fh);
            }

            // row A (row 2t): Q from prev row (frame F -> g via fQ)
            float QA[8];
            QA[0] = eDiagA0 + fQ * Ep[0];
            #pragma unroll
            for (int c = 1; c < 8; ++c) QA[c] = fQ * (Ep[c - 1] + Ep[c]);
            float EA[8];
            {
                float e = eLeftA;
                #pragma unroll
                for (int c = 0; c < 8; ++c) {
                    e = __builtin_fmaf(endA[c], e, endA[c] * QA[c]);
                    EA[c] = e;
                }
            }

            // row B (row 2t+1): same frame g, Q directly from EA
            float eDiagB0 = (l == 0) ? 0.0f : E7sA * factor;
            float eLeftB  = (l == 0) ? 0.0f : E7sB * factor;
            float QB[8];
            QB[0] = eDiagB0 + EA[0];
            #pragma unroll
            for (int c = 1; c < 8; ++c) QB[c] = EA[c - 1] + EA[c];
            float EB[8];
            {
                float e = eLeftB;
                #pragma unroll
                for (int c = 0; c < 8; ++c) {
                    e = __builtin_fmaf(endB[c], e, endB[c] * QB[c]);
                    EB[c] = e;
                }
            }

            // recover r = g - log(E) and store (off the serial chain)
            float outA[8], outB[8];
            #pragma unroll
            for (int c = 0; c < 8; ++c) outA[c] = g - __logf(EA[c]);
            #pragma unroll
            for (int c = 0; c < 8; ++c) outB[c] = g - __logf(EB[c]);
            float4* r0 = (float4*)(Rb + (size_t)i0 * M_DIM + c0);
            r0[0] = make_float4(outA[0], outA[1], outA[2], outA[3]);
            r0[1] = make_float4(outA[4], outA[5], outA[6], outA[7]);
            float4* r1 = (float4*)(Rb + (size_t)(i0 + 1) * M_DIM + c0);
            r1[0] = make_float4(outB[0], outB[1], outB[2], outB[3]);
            r1[1] = make_float4(outB[4], outB[5], outB[6], outB[7]);

            // next-step frame bookkeeping (off-chain)
            const float gn = outB[0];
            fQ = __expf(gn - g);
            F  = g;
            G  = gn;
            #pragma unroll
            for (int c = 0; c < 8; ++c) Ep[c] = EB[c];
            expA7 = EA[7];
            expB7 = EB[7];
        }

        // history update (all lanes, after use)
        E7hB = E7sB;
        Fh   = Fs;

        // convert pair t+1 (this slot, loaded 3 steps ago) -> endA/endB
        endA[0] = __expf(-qA0.x); endA[1] = __expf(-qA0.y);
        endA[2] = __expf(-qA0.z); endA[3] = __expf(-qA0.w);
        endA[4] = __expf(-qA1.x); endA[5] = __expf(-qA1.y);
        endA[6] = __expf(-qA1.z); endA[7] = __expf(-qA1.w);
        endB[0] = __expf(-qB0.x); endB[1] = __expf(-qB0.y);
        endB[2] = __expf(-qB0.z); endB[3] = __expf(-qB0.w);
        endB[4] = __expf(-qB1.x); endB[5] = __expf(-qB1.y);
        endB[6] = __expf(-qB1.z); endB[7] = __expf(-qB1.w);

        // reload this slot with pair t+4 (rows 2t+8, 2t+9)
        loadrow(2 * t + 8, qA0, qA1);
        loadrow(2 * t + 9, qB0, qB1);
    };

    for (int s = 0; s < TSTEPS; s += 3) {
        step_body(s + 0, s0A0, s0A1, s0B0, s0B1);
        step_body(s + 1, s1A0, s1A1, s1B0, s1B1);
        step_body(s + 2, s2A0, s2A1, s2B0, s2B1);
    }
}

extern "C" void kernel_launch(void* const* d_in, const int* in_sizes, int n_in,
                              void* d_out, int out_size, void* d_ws, size_t ws_size,
                              hipStream_t stream) {
    const float* x = (const float*)d_in[0];
    float* out     = (float*)d_out;
    const int B    = in_sizes[0] / (N_DIM * M_DIM);
    softdtw_kernel<<<dim3(B), dim3(64), 0, stream>>>(x, out);
}